// Round 15
// baseline (492.364 us; speedup 1.0000x reference)
//
#include <hip/hip_runtime.h>

#define Bc 8
#define Tc 8
#define Cc 32
#define Hc 16
#define Wc 28
#define NHc 4
#define DKc 8
#define HWc (Hc*Wc)                  // 448
#define INV_SCALE 0.35355339059327373f
#define LOG2E 1.4426950408889634f
#define LN2H ((_Float16)0.6931471805599453f)
#define LN_EPSc 1e-5f

typedef _Float16 half8  __attribute__((ext_vector_type(8)));
typedef _Float16 half2v __attribute__((ext_vector_type(2)));

union H8 { half8 v; half2v h2[4]; };

// Workspace layouts:
//   Qh    : [bh][t][hw]    half8   (LN'd, pre-scaled by INV_SCALE*log2e)
//   Kh    : [bh][s][hw]    half8
//   Vh    : [bh][s][hw]    half8
//   Tpart : [bh][s][t][hw] half8   (fp16 partials, ln2-rescaled) = 4*N5 floats
//   LM    : [bh][s][t][hw] float2  (l = sum 2^sc', m' = max sc' [log2 domain])
//   cnt   : 16 x unsigned  (completion counters, zeroed by qkv)
//
// R11 lesson: accumulators must be NAMED registers (indexed 2-D arrays are
// demoted to scratch -> 195 MB HBM traffic).
// R12 lesson: fp16 V pays only if never converted (v_pk_fma_f16 accumulate).
// R14 lesson: __exp2f collides with glibc math.h -- use __builtin_amdgcn_exp2f.

// ---------------------------------------------------------------------------
// Kernel 1: QKV projection + fused LayerNorm of q.
// grid = 256, 448 threads.  blk = head*64 + bt (XCD co-location).
// Also zeroes the 16 attn completion counters (block 0).
// ---------------------------------------------------------------------------
__global__ __launch_bounds__(448) void qkv_ln_kernel(
    const float* __restrict__ first, const float* __restrict__ x,
    const float* __restrict__ Wq, const float* __restrict__ Wk,
    const float* __restrict__ Wv,
    const float* __restrict__ gamma, const float* __restrict__ beta,
    half8* __restrict__ Qh, half8* __restrict__ Kh, half8* __restrict__ Vh,
    unsigned* __restrict__ cnt)
{
    int blk  = blockIdx.x;           // head*64 + bt
    int head = blk >> 6;
    int bt   = blk & 63;             // b*T + t
    int t    = bt % Tc;
    int b    = bt / Tc;
    int tid  = threadIdx.x;          // h*W + w

    if (blk == 0 && tid < 16) cnt[tid] = 0;   // ordered before attn dispatch

    const float* fp = first + (size_t)bt * Cc * HWc + tid;
    const float* xp = x     + (size_t)bt * Cc * HWc + tid;
    float fv[Cc], xv[Cc];
#pragma unroll
    for (int c = 0; c < Cc; ++c) { fv[c] = fp[c*HWc]; xv[c] = xp[c*HWc]; }

    float qv[DKc], kv[DKc], vv[DKc];
#pragma unroll
    for (int dk = 0; dk < DKc; ++dk) {
        int o = head*DKc + dk;       // lane-uniform -> scalar loads of weights
        float aq = 0.f, ak = 0.f, av = 0.f;
#pragma unroll
        for (int c = 0; c < Cc; ++c) {
            aq = fmaf(Wq[o*Cc+c], fv[c], aq);
            ak = fmaf(Wk[o*Cc+c], xv[c], ak);
            av = fmaf(Wv[o*Cc+c], xv[c], av);
        }
        qv[dk] = aq; kv[dk] = ak; vv[dk] = av;
    }

    int bh = b*NHc + head;
    half8 kh, vh;
#pragma unroll
    for (int dk = 0; dk < DKc; ++dk) {
        kh[dk] = (_Float16)kv[dk];
        vh[dk] = (_Float16)vv[dk];
    }
    Kh[((size_t)bh*Tc + t)*HWc + tid] = kh;
    Vh[((size_t)bh*Tc + t)*HWc + tid] = vh;

    // LayerNorm over (DK,H,W) = 3584 values for this (b,t,head)
    float s1 = 0.f, s2 = 0.f;
#pragma unroll
    for (int dk = 0; dk < DKc; ++dk) { s1 += qv[dk]; s2 += qv[dk]*qv[dk]; }
#pragma unroll
    for (int off = 32; off >= 1; off >>= 1) {
        s1 += __shfl_down(s1, off, 64);
        s2 += __shfl_down(s2, off, 64);
    }
    __shared__ float r1[8], r2[8];
    int wid = tid >> 6, lane = tid & 63;
    if (lane == 0) { r1[wid] = s1; r2[wid] = s2; }
    __syncthreads();
    float S1 = 0.f, S2 = 0.f;
#pragma unroll
    for (int wv2 = 0; wv2 < 7; ++wv2) { S1 += r1[wv2]; S2 += r2[wv2]; }
    const float invN = 1.f / (float)(DKc * HWc);
    float mu   = S1 * invN;
    float var  = S2 * invN - mu*mu;
    float rstd = rsqrtf(var + LN_EPSc);

    const float QSC = INV_SCALE * LOG2E;     // scores come out in log2 domain
    half8 qh;
#pragma unroll
    for (int dk = 0; dk < DKc; ++dk) {
        float gg = gamma[dk*HWc + tid];
        float bb = beta [dk*HWc + tid];
        qh[dk] = (_Float16)(((qv[dk] - mu) * rstd * gg + bb) * QSC);
    }
    Qh[((size_t)bh*Tc + t)*HWc + tid] = qh;
}

// ---------------------------------------------------------------------------
// Kernel 2: attention + fused epilogue.  t_batch = 4, grid = 512 blocks.
// Stride-256 complementary-head pairing: blk and blk+256 co-resident on one
// CU; blk<256 -> heads {0,1}, blk>=256 -> heads {3,2} (heavy+light mix).
// Scores in log2 domain (q pre-scaled by log2e): l += exp2 (native
// v_exp_f32, no hidden mul); partials rescaled by ln2 at store.
// Epilogue: per (b,th) completion counter; the 32nd block (4 heads x 8 s)
// combines partials and projects its 4 t's -- outproj dispatch eliminated.
// ---------------------------------------------------------------------------
__global__ __launch_bounds__(448, 4) void attn_kernel(
    const half8* __restrict__ Qh, const half8* __restrict__ Kh,
    const half8* __restrict__ Vh,
    half8* __restrict__ Tpart, float2* __restrict__ LMpart,
    const float* __restrict__ Wo, float* __restrict__ out,
    unsigned* __restrict__ cnt)
{
    int blk = blockIdx.x;
    int p   = blk >> 8;              // pairing half
    int i   = blk & 255;
    int b   = i >> 5;
    int ha  = (i >> 4) & 1;
    int s   = (i >> 1) & 7;
    int th  = i & 1;

    int head = p ? (3 - ha) : ha;
    int dil  = 2*head + 1;           // {1,3,5,7}
    int bh   = b*NHc + head;
    int t0   = th*4;

    int tid = threadIdx.x;           // h*W + w
    int w = tid % Wc;
    int h = tid / Wc;

    // LDS: K/V staging during main loop, re-used as mvs/ps in the epilogue.
    __shared__ __align__(16) char smem[17024];
    half8* sK = (half8*)smem;                       // [HWc+1]
    half8* sV = (half8*)(smem + (HWc+1)*sizeof(half8));
    __shared__ int last_flag;

    sK[tid] = Kh[((size_t)bh*Tc + s)*HWc + tid];
    sV[tid] = Vh[((size_t)bh*Tc + s)*HWc + tid];
    if (tid == 0) {
        half8 z = {};
        sK[HWc] = z;
        sV[HWc] = z;
    }

    H8 q0, q1, q2, q3;
    {
        const half8* qb = Qh + ((size_t)bh*Tc + t0)*HWc + tid;
        q0.v = qb[0*HWc]; q1.v = qb[1*HWc]; q2.v = qb[2*HWc]; q3.v = qb[3*HWc];
    }

    half8 a0 = {}, a1 = {}, a2 = {}, a3 = {};
    float l0 = 0.f, l1 = 0.f, l2 = 0.f, l3 = 0.f;
    float m0 = -1e30f, m1 = -1e30f, m2 = -1e30f, m3 = -1e30f;

    __syncthreads();

    for (int dy = -3; dy <= 3; ++dy) {
        int hy = h + dy*dil;
        if ((unsigned)hy >= (unsigned)Hc) continue;   // exec-mask row skip
        int rowbase = hy*Wc;
#pragma unroll
        for (int dx = -3; dx <= 3; ++dx) {
            int wx = w + dx*dil;
            bool cv = (unsigned)wx < (unsigned)Wc;
            int idx = cv ? (rowbase + wx) : HWc;      // zero slot if invalid
            float bias = cv ? 0.f : -1e30f;
            H8 k; k.v = sK[idx];
            half8 vh = sV[idx];

#define ATTN_STEP(qq, acc, ll, mm)                                            \
            {                                                                 \
                float sc = __builtin_amdgcn_fdot2(qq.h2[0], k.h2[0],          \
                           __builtin_amdgcn_fdot2(qq.h2[1], k.h2[1],          \
                           __builtin_amdgcn_fdot2(qq.h2[2], k.h2[2],          \
                           __builtin_amdgcn_fdot2(qq.h2[3], k.h2[3],          \
                                                  0.f, false), false), false), false); \
                float msc = sc + bias;                                        \
                mm = fmaxf(mm, msc);                                          \
                ll += __builtin_amdgcn_exp2f(msc);                            \
                _Float16 sh = (_Float16)sc;                                   \
                half8 scb = { sh, sh, sh, sh, sh, sh, sh, sh };               \
                acc += scb * vh;   /* v_pk_fma_f16; invalid: k=0 -> sc=0 */   \
            }
            ATTN_STEP(q0, a0, l0, m0)
            ATTN_STEP(q1, a1, l1, m1)
            ATTN_STEP(q2, a2, l2, m2)
            ATTN_STEP(q3, a3, l3, m3)
#undef ATTN_STEP
        }
    }

    // Undo the log2e scaling of the value-path accumulators (ln2 factor).
    half8 lnc = { LN2H, LN2H, LN2H, LN2H, LN2H, LN2H, LN2H, LN2H };
    a0 *= lnc; a1 *= lnc; a2 *= lnc; a3 *= lnc;

    half8*  tp  = Tpart  + (size_t)(bh*Tc + s)*Tc*HWc + tid;
    float2* lmp = LMpart + (size_t)(bh*Tc + s)*Tc*HWc + tid;
    tp [(t0+0)*HWc] = a0;  lmp[(t0+0)*HWc] = make_float2(l0, m0);
    tp [(t0+1)*HWc] = a1;  lmp[(t0+1)*HWc] = make_float2(l1, m1);
    tp [(t0+2)*HWc] = a2;  lmp[(t0+2)*HWc] = make_float2(l2, m2);
    tp [(t0+3)*HWc] = a3;  lmp[(t0+3)*HWc] = make_float2(l3, m3);

    // ---- completion counting (release my partials, count arrivals) --------
    __threadfence();                 // release: partials visible agent-wide
    __syncthreads();                 // all lanes' stores drained
    if (tid == 0) {
        unsigned old = __hip_atomic_fetch_add(&cnt[b*2 + th], 1u,
                                              __ATOMIC_ACQ_REL,
                                              __HIP_MEMORY_SCOPE_AGENT);
        last_flag = (old == 31u);
    }
    __syncthreads();
    if (!last_flag) return;

    // ---- epilogue (last block of this (b,th) group): combine + project ----
    __threadfence();                 // acquire: invalidate stale L1/L2
    float (*mvs)[33] = (float(*)[33])smem;            // 112 x 33 floats
    float (*ps )[5]  = (float(*)[5])(smem + 112*33*sizeof(float));

    int unit = tid / 112;            // phase-A head / phase-B og
    int hwq  = tid % 112;

#pragma unroll 1
    for (int tt = 0; tt < 4; ++tt) {
        int t = t0 + tt;
#pragma unroll 1
        for (int hq = 0; hq < 4; ++hq) {
            int hw  = hq*112 + hwq;
            int bh2 = b*NHc + unit;

            float4 ac0 = {0,0,0,0}, ac1 = {0,0,0,0};
            float lsum = 0.f, mmax = -1e30f;
#pragma unroll
            for (int ss = 0; ss < Tc; ++ss) {
                size_t base = (size_t)((bh2*Tc + ss)*Tc + t)*HWc + hw;
                half8 tv = Tpart[base];
                ac0.x += (float)tv[0]; ac0.y += (float)tv[1];
                ac0.z += (float)tv[2]; ac0.w += (float)tv[3];
                ac1.x += (float)tv[4]; ac1.y += (float)tv[5];
                ac1.z += (float)tv[6]; ac1.w += (float)tv[7];
                float2 lm = LMpart[base];
                lsum += lm.x; mmax = fmaxf(mmax, lm.y);
            }
            mvs[hwq][unit*DKc+0] = ac0.x; mvs[hwq][unit*DKc+1] = ac0.y;
            mvs[hwq][unit*DKc+2] = ac0.z; mvs[hwq][unit*DKc+3] = ac0.w;
            mvs[hwq][unit*DKc+4] = ac1.x; mvs[hwq][unit*DKc+5] = ac1.y;
            mvs[hwq][unit*DKc+6] = ac1.z; mvs[hwq][unit*DKc+7] = ac1.w;
            ps[hwq][unit] = __builtin_amdgcn_exp2f(mmax) / lsum;
            __syncthreads();

            float MS = fmaxf(fmaxf(ps[hwq][0], ps[hwq][1]),
                             fmaxf(ps[hwq][2], ps[hwq][3]));
            float o0=0.f,o1=0.f,o2=0.f,o3=0.f,o4=0.f,o5=0.f,o6=0.f,o7=0.f;
#pragma unroll
            for (int c = 0; c < Cc; ++c) {
                float mv = mvs[hwq][c];
                o0 = fmaf(Wo[(unit*8+0)*Cc + c], mv, o0);
                o1 = fmaf(Wo[(unit*8+1)*Cc + c], mv, o1);
                o2 = fmaf(Wo[(unit*8+2)*Cc + c], mv, o2);
                o3 = fmaf(Wo[(unit*8+3)*Cc + c], mv, o3);
                o4 = fmaf(Wo[(unit*8+4)*Cc + c], mv, o4);
                o5 = fmaf(Wo[(unit*8+5)*Cc + c], mv, o5);
                o6 = fmaf(Wo[(unit*8+6)*Cc + c], mv, o6);
                o7 = fmaf(Wo[(unit*8+7)*Cc + c], mv, o7);
            }
            size_t ob = ((size_t)(b*Tc + t)*Cc)*HWc + hw;
            out[ob + (unit*8+0)*HWc] = o0 * MS;
            out[ob + (unit*8+1)*HWc] = o1 * MS;
            out[ob + (unit*8+2)*HWc] = o2 * MS;
            out[ob + (unit*8+3)*HWc] = o3 * MS;
            out[ob + (unit*8+4)*HWc] = o4 * MS;
            out[ob + (unit*8+5)*HWc] = o5 * MS;
            out[ob + (unit*8+6)*HWc] = o6 * MS;
            out[ob + (unit*8+7)*HWc] = o7 * MS;
            __syncthreads();         // mvs/ps reused next iteration
        }
    }
}

// ---------------------------------------------------------------------------
extern "C" void kernel_launch(void* const* d_in, const int* in_sizes, int n_in,
                              void* d_out, int out_size, void* d_ws, size_t ws_size,
                              hipStream_t stream) {
    const float* first = (const float*)d_in[0];
    const float* x     = (const float*)d_in[1];
    const float* Wq    = (const float*)d_in[2];
    const float* Wk    = (const float*)d_in[3];
    const float* Wv    = (const float*)d_in[4];
    const float* Wo    = (const float*)d_in[5];
    const float* g     = (const float*)d_in[6];
    const float* bta   = (const float*)d_in[7];
    float* out = (float*)d_out;

    float* ws = (float*)d_ws;
    const size_t N5 = (size_t)Bc*NHc*Tc*HWc*DKc;    // 917504 elements
    half8*    Qh  = (half8*)ws;                      // N5/2 floats
    half8*    Kh  = (half8*)(ws + N5/2);             // N5/2 floats
    half8*    Vh  = (half8*)(ws + N5);               // N5/2 floats
    half8*    Tp  = (half8*)(ws + 3*N5/2);           // 4*N5 floats
    float2*   LMp = (float2*)(ws + 3*N5/2 + 4*N5);   // 2*N5 floats
    unsigned* cnt = (unsigned*)(ws + 3*N5/2 + 6*N5); // 16 counters
    // total: ~27.5 MB

    qkv_ln_kernel<<<Bc*Tc*NHc, 448, 0, stream>>>(first, x, Wq, Wk, Wv, g, bta,
                                                 Qh, Kh, Vh, cnt);
    attn_kernel  <<<512,       448, 0, stream>>>(Qh, Kh, Vh, Tp, LMp, Wo, out, cnt);
}